// Round 6
// baseline (1476.133 us; speedup 1.0000x reference)
//
#include <hip/hip_runtime.h>

typedef _Float16 half8 __attribute__((ext_vector_type(8)));
typedef float f32x4 __attribute__((ext_vector_type(4)));

#define B_ 4
#define C_ 64
#define N_ 8192
#define K_ 20
#define LCELL 10                  // per-lane per-query sorted list depth
#define NCAND (16 * LCELL)        // 160 candidates per query into refine
#define CNT_TOTAL (B_ * N_ * K_)  // 655360
#define BN_EPSF 1e-5f

// ---- Kernel 1: transpose x -> xt (f32 + f16), per-point sq (f32+f64),
// y1 = xt*W1^T, y2 = xt*W2^T - y1. W row o==lane held in 128 VGPRs.
__global__ __launch_bounds__(256) void prep_kernel(
    const float* __restrict__ x, const float* __restrict__ W,
    float* __restrict__ xt, _Float16* __restrict__ xt16,
    float* __restrict__ sq, double* __restrict__ sqd,
    float* __restrict__ y1, float* __restrict__ y2) {
  __shared__ float xs[64 * 68];  // [n][c], stride 68 (16B-aligned rows)
  int b = blockIdx.x >> 7;
  int n0 = (blockIdx.x & 127) * 64;
  int t = threadIdx.x;
  int lane = t & 63;
  int wv = t >> 6;
#pragma unroll
  for (int i = 0; i < 16; ++i) {
    int lin = i * 256 + t;
    int c = lin >> 6, j = lin & 63;
    xs[j * 68 + c] = x[((b * 64 + c) * N_) + n0 + j];
  }
  // W row o = lane into registers (L1/L2-hot, 32 KB total)
  float4 w1[16], w2[16];
  const float4* wr = (const float4*)(W + lane * 128);
#pragma unroll
  for (int u = 0; u < 16; ++u) {
    w1[u] = wr[u];
    w2[u] = wr[16 + u];
  }
  __syncthreads();
#pragma unroll 2
  for (int i = 0; i < 16; ++i) {
    int nl = i * 4 + wv;
    const float4* xr = (const float4*)&xs[nl * 68];
    float d1 = 0.f, d2 = 0.f;
#pragma unroll
    for (int u = 0; u < 16; ++u) {
      float4 xv = xr[u];
      d1 = fmaf(xv.x, w1[u].x, d1); d1 = fmaf(xv.y, w1[u].y, d1);
      d1 = fmaf(xv.z, w1[u].z, d1); d1 = fmaf(xv.w, w1[u].w, d1);
      d2 = fmaf(xv.x, w2[u].x, d2); d2 = fmaf(xv.y, w2[u].y, d2);
      d2 = fmaf(xv.z, w2[u].z, d2); d2 = fmaf(xv.w, w2[u].w, d2);
    }
    int n = n0 + nl;
    y1[((b * N_) + n) * 64 + lane] = d1;
    y2[((b * N_) + n) * 64 + lane] = d2 - d1;
  }
#pragma unroll
  for (int i = 0; i < 16; ++i) {
    int lin = i * 256 + t;
    int c = lin & 63, nl = lin >> 6;
    float v = xs[nl * 68 + c];
    size_t o = ((size_t)(b * N_) + n0 + nl) * 64 + c;
    xt[o] = v;
    xt16[o] = (_Float16)v;
  }
  if (t < 64) {
    float s = 0.f;
    double sd = 0.0;
#pragma unroll
    for (int c = 0; c < 64; ++c) {
      float v = xs[t * 68 + c];
      s = fmaf(v, v, s);
      sd = fma((double)v, (double)v, sd);
    }
    sq[b * N_ + n0 + t] = s;
    sqd[b * N_ + n0 + t] = sd;
  }
}

// ---- Kernel 2: MFMA distance scan, branchless med3 top-10 per (query,class).
// Packed key: (float_bits(sqc+512-2dot) & ~511) | tile_id. Self not excluded
// (refine drops it). No LDS; B-frags stream from L2, software-pipelined.
__global__ __launch_bounds__(256) void knn_mfma_kernel(
    const _Float16* __restrict__ xt16, const float* __restrict__ sq,
    int* __restrict__ pidx) {
  int t = threadIdx.x;
  int wave = t >> 6;
  int lane = t & 63;
  int col = lane & 15;
  int quad = lane >> 4;
  int b = blockIdx.x >> 7;
  int q0 = (blockIdx.x & 127) * 64 + wave * 16;
  size_t bbase = (size_t)b * N_;

  // A fragments: A[m=col][k=quad*8+j] -> query row q0+col
  const _Float16* arow = xt16 + (bbase + q0 + col) * 64;
  half8 A0 = *(const half8*)(arow + quad * 8);
  half8 A1 = *(const half8*)(arow + 32 + quad * 8);

  int dl[4][LCELL];
#pragma unroll
  for (int r = 0; r < 4; ++r)
#pragma unroll
    for (int j = 0; j < LCELL; ++j) dl[r][j] = 0x7fffffff;

  const _Float16* brow0 = xt16 + (bbase + col) * 64;
  half8 B0 = *(const half8*)(brow0 + quad * 8);
  half8 B1 = *(const half8*)(brow0 + 32 + quad * 8);
  float sqc512 = sq[bbase + col] + 512.0f;

  for (int ct = 0; ct < N_ / 16; ++ct) {
    int nct = (ct + 1) & (N_ / 16 - 1);
    const _Float16* nbrow = xt16 + (bbase + nct * 16 + col) * 64;
    half8 nB0 = *(const half8*)(nbrow + quad * 8);
    half8 nB1 = *(const half8*)(nbrow + 32 + quad * 8);
    float nsqc = sq[bbase + nct * 16 + col];

    f32x4 acc = {0.f, 0.f, 0.f, 0.f};
    acc = __builtin_amdgcn_mfma_f32_16x16x32_f16(A0, B0, acc, 0, 0, 0);
    acc = __builtin_amdgcn_mfma_f32_16x16x32_f16(A1, B1, acc, 0, 0, 0);
#pragma unroll
    for (int r = 0; r < 4; ++r) {
      float key = fmaf(acc[r], -2.0f, sqc512);  // positive by construction
      int v = (__float_as_int(key) & ~511) | ct;
#pragma unroll
      for (int j = LCELL - 1; j >= 1; --j)
        dl[r][j] = min(max(v, dl[r][j - 1]), dl[r][j]);  // -> v_med3_i32
      dl[r][0] = min(dl[r][0], v);
    }
    B0 = nB0; B1 = nB1; sqc512 = nsqc + 512.0f;
  }
#pragma unroll
  for (int r = 0; r < 4; ++r) {
    int q = q0 + quad * 4 + r;
    int* o = pidx + (bbase + q) * NCAND + col * LCELL;
#pragma unroll
    for (int j = 0; j < LCELL; ++j) o[j] = (dl[r][j] & 511) * 16 + col;
  }
}

// ---- Kernel 3: fp64 refinement, 4 threads per point (40 candidates each).
// key = sqd - 2*dot64 + 1024 (positive); 13-bit index embedded in low
// mantissa (exact ranking + lower-index tie-break). Per-thread branchless
// top-20, then 4-way sorted-list pop-min merge in LDS (keys unique).
__global__ __launch_bounds__(256, 2) void refine_kernel(
    const float* __restrict__ xt, const double* __restrict__ sqd,
    const int* __restrict__ pidx, int* __restrict__ idxf) {
  __shared__ double lists[256][21];  // 43 KB: 20 entries + sentinel
  int tid = threadIdx.x;
  int p = blockIdx.x * 64 + (tid >> 2);  // global point id
  int h = tid & 3;                       // candidate quarter
  int b = p >> 13;
  size_t bbase = (size_t)b * N_;
  int plocal = p & (N_ - 1);

  const float4* qrow = (const float4*)(xt + (size_t)p * 64);
  double qd[64];
#pragma unroll
  for (int u = 0; u < 16; ++u) {
    float4 v = qrow[u];
    qd[u * 4 + 0] = (double)v.x; qd[u * 4 + 1] = (double)v.y;
    qd[u * 4 + 2] = (double)v.z; qd[u * 4 + 3] = (double)v.w;
  }
  double dl[K_];
#pragma unroll
  for (int j = 0; j < K_; ++j) dl[j] = 1e300;
  const int* pi = pidx + (size_t)p * NCAND + h * (NCAND / 4);
#pragma unroll 2
  for (int e = 0; e < NCAND / 4; ++e) {
    int ci = pi[e];
    const float4* crow = (const float4*)(xt + (bbase + ci) * 64);
    double a0 = 0.0, a1 = 0.0, a2 = 0.0, a3 = 0.0;
#pragma unroll
    for (int u = 0; u < 16; ++u) {
      float4 v = crow[u];
      a0 = fma((double)v.x, qd[u * 4 + 0], a0);
      a1 = fma((double)v.y, qd[u * 4 + 1], a1);
      a2 = fma((double)v.z, qd[u * 4 + 2], a2);
      a3 = fma((double)v.w, qd[u * 4 + 3], a3);
    }
    double dot = (a0 + a1) + (a2 + a3);
    double kd = fma(dot, -2.0, sqd[bbase + ci]) + 1024.0;  // in (894,1414)
    long long bits = (__double_as_longlong(kd) & ~0x1FFFLL) | (long long)ci;
    double v = __longlong_as_double(bits);
    if (ci == plocal) v = 1e300;  // self-exclusion
#pragma unroll
    for (int j = K_ - 1; j >= 1; --j)
      dl[j] = fmin(fmax(v, dl[j - 1]), dl[j]);
    dl[0] = fmin(dl[0], v);
  }
#pragma unroll
  for (int j = 0; j < K_; ++j) lists[tid][j] = dl[j];
  lists[tid][K_] = 1e300;  // sentinel
  __syncthreads();
  if (h == 0) {
    const double* L0 = lists[tid + 0];
    const double* L1 = lists[tid + 1];
    const double* L2 = lists[tid + 2];
    const double* L3 = lists[tid + 3];
    int h0 = 0, h1 = 0, h2 = 0, h3 = 0;
    int* o = idxf + (size_t)p * K_;
#pragma unroll 4
    for (int s = 0; s < K_; ++s) {
      double v0 = L0[h0], v1 = L1[h1], v2 = L2[h2], v3 = L3[h3];
      double m = fmin(fmin(v0, v1), fmin(v2, v3));
      o[s] = (int)(__double_as_longlong(m) & 0x1FFFLL);
      h0 += (v0 == m) ? 1 : 0;
      h1 += (v1 == m) ? 1 : 0;
      h2 += (v2 == m) ? 1 : 0;
      h3 += (v3 == m) ? 1 : 0;
    }
  }
}

// ---- Kernel 4: gather h = y1[idx] + y2; 8 threads per point (8 ch each);
// per-(b,n,o) max/min; global per-channel sum / sumsq via shuffle + atomics.
// __launch_bounds__(256,4): 128-VGPR budget, no spill (acc set = 40 VGPRs).
__global__ __launch_bounds__(256, 4) void stats_kernel(
    const float* __restrict__ y1, const float* __restrict__ y2,
    const int* __restrict__ idxf, float* __restrict__ maxh,
    float* __restrict__ minh, float* __restrict__ gsum,
    float* __restrict__ gsq) {
  int gid = blockIdx.x * 256 + threadIdx.x;
  int p = gid >> 3;      // point
  int h = gid & 7;       // channel group (8 floats)
  int nb = (p >> 13) * N_;
  const float FINF = __builtin_inff();
  const int* ip = idxf + (size_t)p * K_;
  int nbr[K_];
#pragma unroll
  for (int j = 0; j < K_; ++j) nbr[j] = ip[j];

  float y2c[8];
  const float4* y2r = (const float4*)(y2 + (size_t)p * 64 + h * 8);
#pragma unroll
  for (int u = 0; u < 2; ++u) {
    float4 v = y2r[u];
    y2c[u * 4 + 0] = v.x; y2c[u * 4 + 1] = v.y;
    y2c[u * 4 + 2] = v.z; y2c[u * 4 + 3] = v.w;
  }
  float smax[8], smin[8], ssum[8], ssq[8];
#pragma unroll
  for (int i = 0; i < 8; ++i) {
    smax[i] = -FINF; smin[i] = FINF; ssum[i] = 0.f; ssq[i] = 0.f;
  }
#pragma unroll
  for (int j = 0; j < K_; ++j) {
    const float4* g =
        (const float4*)(y1 + ((size_t)(nb + nbr[j])) * 64 + h * 8);
#pragma unroll
    for (int u = 0; u < 2; ++u) {
      float4 v = g[u];
      float h0 = v.x + y2c[u * 4 + 0];
      float h1 = v.y + y2c[u * 4 + 1];
      float h2 = v.z + y2c[u * 4 + 2];
      float h3 = v.w + y2c[u * 4 + 3];
      smax[u * 4 + 0] = fmaxf(smax[u * 4 + 0], h0);
      smax[u * 4 + 1] = fmaxf(smax[u * 4 + 1], h1);
      smax[u * 4 + 2] = fmaxf(smax[u * 4 + 2], h2);
      smax[u * 4 + 3] = fmaxf(smax[u * 4 + 3], h3);
      smin[u * 4 + 0] = fminf(smin[u * 4 + 0], h0);
      smin[u * 4 + 1] = fminf(smin[u * 4 + 1], h1);
      smin[u * 4 + 2] = fminf(smin[u * 4 + 2], h2);
      smin[u * 4 + 3] = fminf(smin[u * 4 + 3], h3);
      ssum[u * 4 + 0] += h0; ssum[u * 4 + 1] += h1;
      ssum[u * 4 + 2] += h2; ssum[u * 4 + 3] += h3;
      ssq[u * 4 + 0] = fmaf(h0, h0, ssq[u * 4 + 0]);
      ssq[u * 4 + 1] = fmaf(h1, h1, ssq[u * 4 + 1]);
      ssq[u * 4 + 2] = fmaf(h2, h2, ssq[u * 4 + 2]);
      ssq[u * 4 + 3] = fmaf(h3, h3, ssq[u * 4 + 3]);
    }
  }
  float* mh = maxh + (size_t)p * 64 + h * 8;
  float* nh = minh + (size_t)p * 64 + h * 8;
#pragma unroll
  for (int u = 0; u < 2; ++u) {
    ((float4*)mh)[u] = make_float4(smax[u * 4 + 0], smax[u * 4 + 1],
                                   smax[u * 4 + 2], smax[u * 4 + 3]);
    ((float4*)nh)[u] = make_float4(smin[u * 4 + 0], smin[u * 4 + 1],
                                   smin[u * 4 + 2], smin[u * 4 + 3]);
  }
#pragma unroll
  for (int i = 0; i < 8; ++i) {
    float s = ssum[i], s2 = ssq[i];
#pragma unroll
    for (int off = 8; off <= 32; off <<= 1) {  // reduce lanes w/ same h
      s += __shfl_xor(s, off, 64);
      s2 += __shfl_xor(s2, off, 64);
    }
    if ((threadIdx.x & 63) < 8) {
      atomicAdd(&gsum[h * 8 + i], s);
      atomicAdd(&gsq[h * 8 + i], s2);
    }
  }
}

// ---- Kernel 5: affine + relu + max-over-k selection, transposed store ----
__global__ __launch_bounds__(256) void final_kernel(
    const float* __restrict__ maxh, const float* __restrict__ minh,
    const float* __restrict__ gsum, const float* __restrict__ gsq,
    const float* __restrict__ gamma, const float* __restrict__ beta,
    float* __restrict__ out) {
  __shared__ float sc[64], cc_[64];
  __shared__ float tile[64 * 65];
  int b = blockIdx.x >> 7;
  int n0 = (blockIdx.x & 127) * 64;
  int t = threadIdx.x;
  if (t < 64) {
    float mean = gsum[t] * (1.0f / CNT_TOTAL);
    float var = gsq[t] * (1.0f / CNT_TOTAL) - mean * mean;
    float s = gamma[t] * rsqrtf(var + BN_EPSF);
    sc[t] = s;
    cc_[t] = beta[t] - mean * s;
  }
  __syncthreads();
#pragma unroll
  for (int i = 0; i < 16; ++i) {
    int lin = i * 256 + t;
    int o = lin & 63, nl = lin >> 6;
    size_t off = ((size_t)(b * N_) + n0 + nl) * 64 + o;
    float s = sc[o];
    float v = (s >= 0.f) ? maxh[off] : minh[off];
    float val = fmaxf(fmaf(v, s, cc_[o]), 0.f);
    tile[o * 65 + nl] = val;
  }
  __syncthreads();
#pragma unroll
  for (int i = 0; i < 16; ++i) {
    int lin = i * 256 + t;
    int nl = lin & 63, o = lin >> 6;
    out[((size_t)(b * 64) + o) * N_ + n0 + nl] = tile[o * 65 + nl];
  }
}

extern "C" void kernel_launch(void* const* d_in, const int* in_sizes, int n_in,
                              void* d_out, int out_size, void* d_ws,
                              size_t ws_size, hipStream_t stream) {
  const float* x = (const float*)d_in[0];
  const float* W = (const float*)d_in[1];
  const float* gamma = (const float*)d_in[2];
  const float* beta = (const float*)d_in[3];
  float* out = (float*)d_out;

  char* ws = (char*)d_ws;
  size_t off = 0;
  auto alloc = [&](size_t bytes) {
    char* p = ws + off;
    off += (bytes + 255) & ~(size_t)255;
    return p;
  };
  float* xt = (float*)alloc((size_t)B_ * N_ * 64 * 4);
  _Float16* xt16 = (_Float16*)alloc((size_t)B_ * N_ * 64 * 2);
  float* y1 = (float*)alloc((size_t)B_ * N_ * 64 * 4);
  float* y2 = (float*)alloc((size_t)B_ * N_ * 64 * 4);
  float* sq = (float*)alloc((size_t)B_ * N_ * 4);
  double* sqd = (double*)alloc((size_t)B_ * N_ * 8);
  int* pidx = (int*)alloc((size_t)B_ * N_ * NCAND * 4);  // 21 MB
  float* maxh = (float*)alloc((size_t)B_ * N_ * 64 * 4);
  int* idxf = (int*)alloc((size_t)B_ * N_ * K_ * 4);
  float* gsum = (float*)alloc(256);
  float* gsq = (float*)alloc(256);
  // minh aliases pidx (pidx fully consumed by refine before stats runs)
  float* minh = (float*)pidx;

  hipMemsetAsync(gsum, 0, 256, stream);
  hipMemsetAsync(gsq, 0, 256, stream);

  prep_kernel<<<B_ * (N_ / 64), 256, 0, stream>>>(x, W, xt, xt16, sq, sqd,
                                                  y1, y2);
  knn_mfma_kernel<<<B_ * (N_ / 64), 256, 0, stream>>>(xt16, sq, pidx);
  refine_kernel<<<(B_ * N_) / 64, 256, 0, stream>>>(xt, sqd, pidx, idxf);
  stats_kernel<<<(B_ * N_ * 8) / 256, 256, 0, stream>>>(y1, y2, idxf, maxh,
                                                        minh, gsum, gsq);
  final_kernel<<<B_ * (N_ / 64), 256, 0, stream>>>(maxh, minh, gsum, gsq,
                                                   gamma, beta, out);
}

// Round 7
// 687.387 us; speedup vs baseline: 2.1475x; 2.1475x over previous
//
#include <hip/hip_runtime.h>

typedef _Float16 half8 __attribute__((ext_vector_type(8)));
typedef float f32x4 __attribute__((ext_vector_type(4)));

#define B_ 4
#define C_ 64
#define N_ 8192
#define K_ 20
#define LCELL 10                  // per-lane per-query sorted list depth
#define NCAND (16 * LCELL)        // 160 candidates per query into refine
#define CNT_TOTAL (B_ * N_ * K_)  // 655360
#define BN_EPSF 1e-5f

__device__ __forceinline__ f32x4 max4(f32x4 a, f32x4 b) {
  f32x4 r;
  r.x = fmaxf(a.x, b.x); r.y = fmaxf(a.y, b.y);
  r.z = fmaxf(a.z, b.z); r.w = fmaxf(a.w, b.w);
  return r;
}
__device__ __forceinline__ f32x4 min4(f32x4 a, f32x4 b) {
  f32x4 r;
  r.x = fminf(a.x, b.x); r.y = fminf(a.y, b.y);
  r.z = fminf(a.z, b.z); r.w = fminf(a.w, b.w);
  return r;
}

// ---- Kernel 1: transpose x -> xt (f32 + f16), per-point sq (f32+f64),
// y1 = xt*W1^T, y2 = xt*W2^T - y1. W row o==lane held in 128 VGPRs.
__global__ __launch_bounds__(256) void prep_kernel(
    const float* __restrict__ x, const float* __restrict__ W,
    float* __restrict__ xt, _Float16* __restrict__ xt16,
    float* __restrict__ sq, double* __restrict__ sqd,
    float* __restrict__ y1, float* __restrict__ y2) {
  __shared__ float xs[64 * 68];  // [n][c], stride 68 (16B-aligned rows)
  int b = blockIdx.x >> 7;
  int n0 = (blockIdx.x & 127) * 64;
  int t = threadIdx.x;
  int lane = t & 63;
  int wv = t >> 6;
#pragma unroll
  for (int i = 0; i < 16; ++i) {
    int lin = i * 256 + t;
    int c = lin >> 6, j = lin & 63;
    xs[j * 68 + c] = x[((b * 64 + c) * N_) + n0 + j];
  }
  // W row o = lane into registers (L1/L2-hot, 32 KB total)
  float4 w1[16], w2[16];
  const float4* wr = (const float4*)(W + lane * 128);
#pragma unroll
  for (int u = 0; u < 16; ++u) {
    w1[u] = wr[u];
    w2[u] = wr[16 + u];
  }
  __syncthreads();
#pragma unroll 2
  for (int i = 0; i < 16; ++i) {
    int nl = i * 4 + wv;
    const float4* xr = (const float4*)&xs[nl * 68];
    float d1 = 0.f, d2 = 0.f;
#pragma unroll
    for (int u = 0; u < 16; ++u) {
      float4 xv = xr[u];
      d1 = fmaf(xv.x, w1[u].x, d1); d1 = fmaf(xv.y, w1[u].y, d1);
      d1 = fmaf(xv.z, w1[u].z, d1); d1 = fmaf(xv.w, w1[u].w, d1);
      d2 = fmaf(xv.x, w2[u].x, d2); d2 = fmaf(xv.y, w2[u].y, d2);
      d2 = fmaf(xv.z, w2[u].z, d2); d2 = fmaf(xv.w, w2[u].w, d2);
    }
    int n = n0 + nl;
    y1[((b * N_) + n) * 64 + lane] = d1;
    y2[((b * N_) + n) * 64 + lane] = d2 - d1;
  }
#pragma unroll
  for (int i = 0; i < 16; ++i) {
    int lin = i * 256 + t;
    int c = lin & 63, nl = lin >> 6;
    float v = xs[nl * 68 + c];
    size_t o = ((size_t)(b * N_) + n0 + nl) * 64 + c;
    xt[o] = v;
    xt16[o] = (_Float16)v;
  }
  if (t < 64) {
    float s = 0.f;
    double sd = 0.0;
#pragma unroll
    for (int c = 0; c < 64; ++c) {
      float v = xs[t * 68 + c];
      s = fmaf(v, v, s);
      sd = fma((double)v, (double)v, sd);
    }
    sq[b * N_ + n0 + t] = s;
    sqd[b * N_ + n0 + t] = sd;
  }
}

// ---- Kernel 2: MFMA distance scan, branchless med3 top-10 per (query,class).
// Packed key: (float_bits(sqc+512-2dot) & ~511) | tile_id. Self not excluded
// (refine drops it). No LDS; B-frags stream from L2, software-pipelined.
__global__ __launch_bounds__(256) void knn_mfma_kernel(
    const _Float16* __restrict__ xt16, const float* __restrict__ sq,
    int* __restrict__ pidx) {
  int t = threadIdx.x;
  int wave = t >> 6;
  int lane = t & 63;
  int col = lane & 15;
  int quad = lane >> 4;
  int b = blockIdx.x >> 7;
  int q0 = (blockIdx.x & 127) * 64 + wave * 16;
  size_t bbase = (size_t)b * N_;

  // A fragments: A[m=col][k=quad*8+j] -> query row q0+col
  const _Float16* arow = xt16 + (bbase + q0 + col) * 64;
  half8 A0 = *(const half8*)(arow + quad * 8);
  half8 A1 = *(const half8*)(arow + 32 + quad * 8);

  int dl[4][LCELL];
#pragma unroll
  for (int r = 0; r < 4; ++r)
#pragma unroll
    for (int j = 0; j < LCELL; ++j) dl[r][j] = 0x7fffffff;

  const _Float16* brow0 = xt16 + (bbase + col) * 64;
  half8 B0 = *(const half8*)(brow0 + quad * 8);
  half8 B1 = *(const half8*)(brow0 + 32 + quad * 8);
  float sqc512 = sq[bbase + col] + 512.0f;

  for (int ct = 0; ct < N_ / 16; ++ct) {
    int nct = (ct + 1) & (N_ / 16 - 1);
    const _Float16* nbrow = xt16 + (bbase + nct * 16 + col) * 64;
    half8 nB0 = *(const half8*)(nbrow + quad * 8);
    half8 nB1 = *(const half8*)(nbrow + 32 + quad * 8);
    float nsqc = sq[bbase + nct * 16 + col];

    f32x4 acc = {0.f, 0.f, 0.f, 0.f};
    acc = __builtin_amdgcn_mfma_f32_16x16x32_f16(A0, B0, acc, 0, 0, 0);
    acc = __builtin_amdgcn_mfma_f32_16x16x32_f16(A1, B1, acc, 0, 0, 0);
#pragma unroll
    for (int r = 0; r < 4; ++r) {
      float key = fmaf(acc[r], -2.0f, sqc512);  // positive by construction
      int v = (__float_as_int(key) & ~511) | ct;
#pragma unroll
      for (int j = LCELL - 1; j >= 1; --j)
        dl[r][j] = min(max(v, dl[r][j - 1]), dl[r][j]);  // -> v_med3_i32
      dl[r][0] = min(dl[r][0], v);
    }
    B0 = nB0; B1 = nB1; sqc512 = nsqc + 512.0f;
  }
#pragma unroll
  for (int r = 0; r < 4; ++r) {
    int q = q0 + quad * 4 + r;
    int* o = pidx + (bbase + q) * NCAND + col * LCELL;
#pragma unroll
    for (int j = 0; j < LCELL; ++j) o[j] = (dl[r][j] & 511) * 16 + col;
  }
}

// ---- Kernel 3: fp64 refinement, 4 threads per point (40 candidates each).
// key = sqd - 2*dot64 + 1024 (positive); 13-bit index embedded in low
// mantissa (exact ranking + lower-index tie-break). Per-thread branchless
// top-20, then 4-way sorted-list pop-min merge in LDS (keys unique).
__global__ __launch_bounds__(256, 2) void refine_kernel(
    const float* __restrict__ xt, const double* __restrict__ sqd,
    const int* __restrict__ pidx, int* __restrict__ idxf) {
  __shared__ double lists[256][21];  // 43 KB: 20 entries + sentinel
  int tid = threadIdx.x;
  int p = blockIdx.x * 64 + (tid >> 2);  // global point id
  int h = tid & 3;                       // candidate quarter
  int b = p >> 13;
  size_t bbase = (size_t)b * N_;
  int plocal = p & (N_ - 1);

  const float4* qrow = (const float4*)(xt + (size_t)p * 64);
  double qd[64];
#pragma unroll
  for (int u = 0; u < 16; ++u) {
    float4 v = qrow[u];
    qd[u * 4 + 0] = (double)v.x; qd[u * 4 + 1] = (double)v.y;
    qd[u * 4 + 2] = (double)v.z; qd[u * 4 + 3] = (double)v.w;
  }
  double dl[K_];
#pragma unroll
  for (int j = 0; j < K_; ++j) dl[j] = 1e300;
  const int* pi = pidx + (size_t)p * NCAND + h * (NCAND / 4);
#pragma unroll 2
  for (int e = 0; e < NCAND / 4; ++e) {
    int ci = pi[e];
    const float4* crow = (const float4*)(xt + (bbase + ci) * 64);
    double a0 = 0.0, a1 = 0.0, a2 = 0.0, a3 = 0.0;
#pragma unroll
    for (int u = 0; u < 16; ++u) {
      float4 v = crow[u];
      a0 = fma((double)v.x, qd[u * 4 + 0], a0);
      a1 = fma((double)v.y, qd[u * 4 + 1], a1);
      a2 = fma((double)v.z, qd[u * 4 + 2], a2);
      a3 = fma((double)v.w, qd[u * 4 + 3], a3);
    }
    double dot = (a0 + a1) + (a2 + a3);
    double kd = fma(dot, -2.0, sqd[bbase + ci]) + 1024.0;  // in (894,1414)
    long long bits = (__double_as_longlong(kd) & ~0x1FFFLL) | (long long)ci;
    double v = __longlong_as_double(bits);
    if (ci == plocal) v = 1e300;  // self-exclusion
#pragma unroll
    for (int j = K_ - 1; j >= 1; --j)
      dl[j] = fmin(fmax(v, dl[j - 1]), dl[j]);
    dl[0] = fmin(dl[0], v);
  }
#pragma unroll
  for (int j = 0; j < K_; ++j) lists[tid][j] = dl[j];
  lists[tid][K_] = 1e300;  // sentinel
  __syncthreads();
  if (h == 0) {
    const double* L0 = lists[tid + 0];
    const double* L1 = lists[tid + 1];
    const double* L2 = lists[tid + 2];
    const double* L3 = lists[tid + 3];
    int h0 = 0, h1 = 0, h2 = 0, h3 = 0;
    int* o = idxf + (size_t)p * K_;
#pragma unroll 4
    for (int s = 0; s < K_; ++s) {
      double v0 = L0[h0], v1 = L1[h1], v2 = L2[h2], v3 = L3[h3];
      double m = fmin(fmin(v0, v1), fmin(v2, v3));
      o[s] = (int)(__double_as_longlong(m) & 0x1FFFLL);
      h0 += (v0 == m) ? 1 : 0;
      h1 += (v1 == m) ? 1 : 0;
      h2 += (v2 == m) ? 1 : 0;
      h3 += (v3 == m) ? 1 : 0;
    }
  }
}

// ---- Kernel 4: one WAVE per point. Lane (u=lane&15, jb=lane>>4); 5 rounds:
// lane loads 16B chunk u of neighbor jb+4r -> each 16-lane group reads a full
// 256B y1 row per instruction (no partial lines). max/min/sum/sumsq of the
// gathered y1 reduced across jb via shfl_xor(16,32); y2 applied once:
// max(h)=max(g)+y2, sum(h)=sum(g)+K*y2, sumsq(h)=sum(g^2)+2*y2*sum(g)+K*y2^2.
// 4 points per wave sequentially; BN sums -> LDS atomics -> 128 global/block.
__global__ __launch_bounds__(256) void stats_kernel(
    const float* __restrict__ y1, const float* __restrict__ y2,
    const int* __restrict__ idxf, float* __restrict__ maxh,
    float* __restrict__ minh, float* __restrict__ gsum,
    float* __restrict__ gsq) {
  __shared__ float lsum[64], lsq[64];
  int tid = threadIdx.x;
  if (tid < 64) { lsum[tid] = 0.f; lsq[tid] = 0.f; }
  __syncthreads();
  int wv = tid >> 6, lane = tid & 63;
  int u = lane & 15, jb = lane >> 4;
  int p0 = blockIdx.x * 16 + wv * 4;  // 16 contiguous points per block
  size_t nb = (size_t)((p0 >> 13) * N_);
  f32x4 css = {0.f, 0.f, 0.f, 0.f}, cqq = {0.f, 0.f, 0.f, 0.f};
#pragma unroll
  for (int it = 0; it < 4; ++it) {
    int p = p0 + it;
    int idxval = (lane < K_) ? idxf[(size_t)p * K_ + lane] : 0;
    int n0 = __shfl(idxval, jb, 64);
    int n1 = __shfl(idxval, jb + 4, 64);
    int n2 = __shfl(idxval, jb + 8, 64);
    int n3 = __shfl(idxval, jb + 12, 64);
    int n4 = __shfl(idxval, jb + 16, 64);
    f32x4 g0 = ((const f32x4*)(y1 + (nb + n0) * 64))[u];
    f32x4 g1 = ((const f32x4*)(y1 + (nb + n1) * 64))[u];
    f32x4 g2 = ((const f32x4*)(y1 + (nb + n2) * 64))[u];
    f32x4 g3 = ((const f32x4*)(y1 + (nb + n3) * 64))[u];
    f32x4 g4 = ((const f32x4*)(y1 + (nb + n4) * 64))[u];
    f32x4 mx = g0, mn = g0, sm = g0, s2 = g0 * g0;
    mx = max4(mx, g1); mn = min4(mn, g1); sm += g1; s2 += g1 * g1;
    mx = max4(mx, g2); mn = min4(mn, g2); sm += g2; s2 += g2 * g2;
    mx = max4(mx, g3); mn = min4(mn, g3); sm += g3; s2 += g3 * g3;
    mx = max4(mx, g4); mn = min4(mn, g4); sm += g4; s2 += g4 * g4;
#pragma unroll
    for (int c = 0; c < 4; ++c) {
      mx[c] = fmaxf(mx[c], __shfl_xor(mx[c], 16, 64));
      mx[c] = fmaxf(mx[c], __shfl_xor(mx[c], 32, 64));
      mn[c] = fminf(mn[c], __shfl_xor(mn[c], 16, 64));
      mn[c] = fminf(mn[c], __shfl_xor(mn[c], 32, 64));
      sm[c] += __shfl_xor(sm[c], 16, 64);
      sm[c] += __shfl_xor(sm[c], 32, 64);
      s2[c] += __shfl_xor(s2[c], 16, 64);
      s2[c] += __shfl_xor(s2[c], 32, 64);
    }
    if (jb == 0) {  // lanes 0..15: full 256B contiguous stores
      f32x4 y2c = ((const f32x4*)(y2 + (size_t)p * 64))[u];
      ((f32x4*)(maxh + (size_t)p * 64))[u] = mx + y2c;
      ((f32x4*)(minh + (size_t)p * 64))[u] = mn + y2c;
      css += sm + 20.0f * y2c;
      cqq += s2 + 2.0f * y2c * sm + 20.0f * y2c * y2c;
    }
  }
  if (jb == 0) {
#pragma unroll
    for (int c = 0; c < 4; ++c) {
      atomicAdd(&lsum[u * 4 + c], css[c]);
      atomicAdd(&lsq[u * 4 + c], cqq[c]);
    }
  }
  __syncthreads();
  if (tid < 64) {
    atomicAdd(&gsum[tid], lsum[tid]);
    atomicAdd(&gsq[tid], lsq[tid]);
  }
}

// ---- Kernel 5: affine + relu + max-over-k selection, transposed store ----
__global__ __launch_bounds__(256) void final_kernel(
    const float* __restrict__ maxh, const float* __restrict__ minh,
    const float* __restrict__ gsum, const float* __restrict__ gsq,
    const float* __restrict__ gamma, const float* __restrict__ beta,
    float* __restrict__ out) {
  __shared__ float sc[64], cc_[64];
  __shared__ float tile[64 * 65];
  int b = blockIdx.x >> 7;
  int n0 = (blockIdx.x & 127) * 64;
  int t = threadIdx.x;
  if (t < 64) {
    float mean = gsum[t] * (1.0f / CNT_TOTAL);
    float var = gsq[t] * (1.0f / CNT_TOTAL) - mean * mean;
    float s = gamma[t] * rsqrtf(var + BN_EPSF);
    sc[t] = s;
    cc_[t] = beta[t] - mean * s;
  }
  __syncthreads();
#pragma unroll
  for (int i = 0; i < 16; ++i) {
    int lin = i * 256 + t;
    int o = lin & 63, nl = lin >> 6;
    size_t off = ((size_t)(b * N_) + n0 + nl) * 64 + o;
    float s = sc[o];
    float v = (s >= 0.f) ? maxh[off] : minh[off];
    float val = fmaxf(fmaf(v, s, cc_[o]), 0.f);
    tile[o * 65 + nl] = val;
  }
  __syncthreads();
#pragma unroll
  for (int i = 0; i < 16; ++i) {
    int lin = i * 256 + t;
    int nl = lin & 63, o = lin >> 6;
    out[((size_t)(b * 64) + o) * N_ + n0 + nl] = tile[o * 65 + nl];
  }
}

extern "C" void kernel_launch(void* const* d_in, const int* in_sizes, int n_in,
                              void* d_out, int out_size, void* d_ws,
                              size_t ws_size, hipStream_t stream) {
  const float* x = (const float*)d_in[0];
  const float* W = (const float*)d_in[1];
  const float* gamma = (const float*)d_in[2];
  const float* beta = (const float*)d_in[3];
  float* out = (float*)d_out;

  char* ws = (char*)d_ws;
  size_t off = 0;
  auto alloc = [&](size_t bytes) {
    char* p = ws + off;
    off += (bytes + 255) & ~(size_t)255;
    return p;
  };
  float* xt = (float*)alloc((size_t)B_ * N_ * 64 * 4);
  _Float16* xt16 = (_Float16*)alloc((size_t)B_ * N_ * 64 * 2);
  float* y1 = (float*)alloc((size_t)B_ * N_ * 64 * 4);
  float* y2 = (float*)alloc((size_t)B_ * N_ * 64 * 4);
  float* sq = (float*)alloc((size_t)B_ * N_ * 4);
  double* sqd = (double*)alloc((size_t)B_ * N_ * 8);
  int* pidx = (int*)alloc((size_t)B_ * N_ * NCAND * 4);  // 21 MB
  float* maxh = (float*)alloc((size_t)B_ * N_ * 64 * 4);
  int* idxf = (int*)alloc((size_t)B_ * N_ * K_ * 4);
  float* gsum = (float*)alloc(256);
  float* gsq = (float*)alloc(256);
  // minh aliases pidx (pidx fully consumed by refine before stats runs)
  float* minh = (float*)pidx;

  hipMemsetAsync(gsum, 0, 256, stream);
  hipMemsetAsync(gsq, 0, 256, stream);

  prep_kernel<<<B_ * (N_ / 64), 256, 0, stream>>>(x, W, xt, xt16, sq, sqd,
                                                  y1, y2);
  knn_mfma_kernel<<<B_ * (N_ / 64), 256, 0, stream>>>(xt16, sq, pidx);
  refine_kernel<<<(B_ * N_) / 64, 256, 0, stream>>>(xt, sqd, pidx, idxf);
  stats_kernel<<<(B_ * N_) / 16, 256, 0, stream>>>(y1, y2, idxf, maxh, minh,
                                                   gsum, gsq);
  final_kernel<<<B_ * (N_ / 64), 256, 0, stream>>>(maxh, minh, gsum, gsq,
                                                   gamma, beta, out);
}

// Round 8
// 682.884 us; speedup vs baseline: 2.1616x; 1.0066x over previous
//
#include <hip/hip_runtime.h>

typedef _Float16 half8 __attribute__((ext_vector_type(8)));
typedef float f32x4 __attribute__((ext_vector_type(4)));

#define B_ 4
#define C_ 64
#define N_ 8192
#define K_ 20
#define LCELL 8                   // per-(split,class) sorted list depth
#define NSPLIT 2
#define NCAND (16 * LCELL * NSPLIT)  // 256 candidates per query into refine
#define CNT_TOTAL (B_ * N_ * K_)  // 655360
#define BN_EPSF 1e-5f

__device__ __forceinline__ f32x4 max4(f32x4 a, f32x4 b) {
  f32x4 r;
  r.x = fmaxf(a.x, b.x); r.y = fmaxf(a.y, b.y);
  r.z = fmaxf(a.z, b.z); r.w = fmaxf(a.w, b.w);
  return r;
}
__device__ __forceinline__ f32x4 min4(f32x4 a, f32x4 b) {
  f32x4 r;
  r.x = fminf(a.x, b.x); r.y = fminf(a.y, b.y);
  r.z = fminf(a.z, b.z); r.w = fminf(a.w, b.w);
  return r;
}

// ---- Kernel 1: transpose x -> xt (f32 + f16), per-point sq (f32+f64),
// y1 = xt*W1^T, y2 = xt*W2^T - y1. W row o==lane held in 128 VGPRs.
__global__ __launch_bounds__(256) void prep_kernel(
    const float* __restrict__ x, const float* __restrict__ W,
    float* __restrict__ xt, _Float16* __restrict__ xt16,
    float* __restrict__ sq, double* __restrict__ sqd,
    float* __restrict__ y1, float* __restrict__ y2) {
  __shared__ float xs[64 * 68];  // [n][c], stride 68 (16B-aligned rows)
  int b = blockIdx.x >> 7;
  int n0 = (blockIdx.x & 127) * 64;
  int t = threadIdx.x;
  int lane = t & 63;
  int wv = t >> 6;
#pragma unroll
  for (int i = 0; i < 16; ++i) {
    int lin = i * 256 + t;
    int c = lin >> 6, j = lin & 63;
    xs[j * 68 + c] = x[((b * 64 + c) * N_) + n0 + j];
  }
  // W row o = lane into registers (L1/L2-hot, 32 KB total)
  float4 w1[16], w2[16];
  const float4* wr = (const float4*)(W + lane * 128);
#pragma unroll
  for (int u = 0; u < 16; ++u) {
    w1[u] = wr[u];
    w2[u] = wr[16 + u];
  }
  __syncthreads();
#pragma unroll 2
  for (int i = 0; i < 16; ++i) {
    int nl = i * 4 + wv;
    const float4* xr = (const float4*)&xs[nl * 68];
    float d1 = 0.f, d2 = 0.f;
#pragma unroll
    for (int u = 0; u < 16; ++u) {
      float4 xv = xr[u];
      d1 = fmaf(xv.x, w1[u].x, d1); d1 = fmaf(xv.y, w1[u].y, d1);
      d1 = fmaf(xv.z, w1[u].z, d1); d1 = fmaf(xv.w, w1[u].w, d1);
      d2 = fmaf(xv.x, w2[u].x, d2); d2 = fmaf(xv.y, w2[u].y, d2);
      d2 = fmaf(xv.z, w2[u].z, d2); d2 = fmaf(xv.w, w2[u].w, d2);
    }
    int n = n0 + nl;
    y1[((b * N_) + n) * 64 + lane] = d1;
    y2[((b * N_) + n) * 64 + lane] = d2 - d1;
  }
#pragma unroll
  for (int i = 0; i < 16; ++i) {
    int lin = i * 256 + t;
    int c = lin & 63, nl = lin >> 6;
    float v = xs[nl * 68 + c];
    size_t o = ((size_t)(b * N_) + n0 + nl) * 64 + c;
    xt[o] = v;
    xt16[o] = (_Float16)v;
  }
  if (t < 64) {
    float s = 0.f;
    double sd = 0.0;
#pragma unroll
    for (int c = 0; c < 64; ++c) {
      float v = xs[t * 68 + c];
      s = fmaf(v, v, s);
      sd = fma((double)v, (double)v, sd);
    }
    sq[b * N_ + n0 + t] = s;
    sqd[b * N_ + n0 + t] = sd;
  }
}

// ---- Kernel 2: MFMA distance scan over one of 2 candidate splits (4096
// cands). Branchless clamp top-8 per (query,class). Packed key:
// (float_bits(sqc+512-2dot) & ~255) | tile_id(8b). Incremental pointers,
// 2x unrolled (no B-copy movs). __launch_bounds__(256,4): 128-VGPR budget
// so dl[] stays in arch VGPRs (no accvgpr round-trips).
__global__ __launch_bounds__(256, 4) void knn_mfma_kernel(
    const _Float16* __restrict__ xt16, const float* __restrict__ sq,
    int* __restrict__ pidx) {
  int t = threadIdx.x;
  int wave = t >> 6;
  int lane = t & 63;
  int col = lane & 15;
  int quad = lane >> 4;
  int blk = blockIdx.x;
  int split = blk & 1;
  int qt = (blk >> 1) & 127;
  int b = blk >> 8;
  int q0 = qt * 64 + wave * 16;
  size_t bbase = (size_t)b * N_;

  // A fragments: A[m=col][k=quad*8+j] -> query row q0+col
  const _Float16* arow = xt16 + (bbase + q0 + col) * 64;
  half8 A0 = *(const half8*)(arow + quad * 8);
  half8 A1 = *(const half8*)(arow + 32 + quad * 8);

  int dl[4][LCELL];
#pragma unroll
  for (int r = 0; r < 4; ++r)
#pragma unroll
    for (int j = 0; j < LCELL; ++j) dl[r][j] = 0x7fffffff;

  int c0 = split * (N_ / NSPLIT);
  const _Float16* bp = xt16 + (bbase + c0 + col) * 64 + quad * 8;
  const float* sp = sq + bbase + c0 + col;
  half8 B0 = *(const half8*)bp;
  half8 B1 = *(const half8*)(bp + 32);
  float sc = *sp;

  for (int ct = 0; ct < N_ / NSPLIT / 16; ct += 2) {
    // prefetch tile ct+1
    half8 C0 = *(const half8*)(bp + 1024);
    half8 C1 = *(const half8*)(bp + 1024 + 32);
    float sc1 = sp[16];

    f32x4 acc = {0.f, 0.f, 0.f, 0.f};
    acc = __builtin_amdgcn_mfma_f32_16x16x32_f16(A0, B0, acc, 0, 0, 0);
    acc = __builtin_amdgcn_mfma_f32_16x16x32_f16(A1, B1, acc, 0, 0, 0);
    float k512 = sc + 512.0f;
#pragma unroll
    for (int r = 0; r < 4; ++r) {
      float key = fmaf(acc[r], -2.0f, k512);  // positive by construction
      int v = (__float_as_int(key) & ~255) | ct;
#pragma unroll
      for (int j = LCELL - 1; j >= 1; --j)
        dl[r][j] = min(max(v, dl[r][j - 1]), dl[r][j]);
      dl[r][0] = min(dl[r][0], v);
    }

    // prefetch tile ct+2
    B0 = *(const half8*)(bp + 2048);
    B1 = *(const half8*)(bp + 2048 + 32);
    sc = sp[32];

    f32x4 acc2 = {0.f, 0.f, 0.f, 0.f};
    acc2 = __builtin_amdgcn_mfma_f32_16x16x32_f16(A0, C0, acc2, 0, 0, 0);
    acc2 = __builtin_amdgcn_mfma_f32_16x16x32_f16(A1, C1, acc2, 0, 0, 0);
    float k512b = sc1 + 512.0f;
    int ctb = ct + 1;
#pragma unroll
    for (int r = 0; r < 4; ++r) {
      float key = fmaf(acc2[r], -2.0f, k512b);
      int v = (__float_as_int(key) & ~255) | ctb;
#pragma unroll
      for (int j = LCELL - 1; j >= 1; --j)
        dl[r][j] = min(max(v, dl[r][j - 1]), dl[r][j]);
      dl[r][0] = min(dl[r][0], v);
    }
    bp += 2048;
    sp += 32;
  }
#pragma unroll
  for (int r = 0; r < 4; ++r) {
    int q = q0 + quad * 4 + r;
    int* o = pidx + (bbase + q) * NCAND + split * (16 * LCELL) + col * LCELL;
#pragma unroll
    for (int j = 0; j < LCELL; ++j)
      o[j] = ((dl[r][j] & 255) << 4) + col + c0;  // global candidate index
  }
}

// ---- Kernel 3: fp64 refinement, 4 threads per point (64 candidates each).
// key = sqd - 2*dot64 + 1024 (positive); 13-bit index embedded in low
// mantissa (exact ranking + lower-index tie-break). Per-thread branchless
// top-20, then 4-way sorted-list pop-min merge in LDS (keys unique).
__global__ __launch_bounds__(256, 2) void refine_kernel(
    const float* __restrict__ xt, const double* __restrict__ sqd,
    const int* __restrict__ pidx, int* __restrict__ idxf) {
  __shared__ double lists[256][21];  // 43 KB: 20 entries + sentinel
  int tid = threadIdx.x;
  int p = blockIdx.x * 64 + (tid >> 2);  // global point id
  int h = tid & 3;                       // candidate quarter
  int b = p >> 13;
  size_t bbase = (size_t)b * N_;
  int plocal = p & (N_ - 1);

  const float4* qrow = (const float4*)(xt + (size_t)p * 64);
  double qd[64];
#pragma unroll
  for (int u = 0; u < 16; ++u) {
    float4 v = qrow[u];
    qd[u * 4 + 0] = (double)v.x; qd[u * 4 + 1] = (double)v.y;
    qd[u * 4 + 2] = (double)v.z; qd[u * 4 + 3] = (double)v.w;
  }
  double dl[K_];
#pragma unroll
  for (int j = 0; j < K_; ++j) dl[j] = 1e300;
  const int* pi = pidx + (size_t)p * NCAND + h * (NCAND / 4);
#pragma unroll 2
  for (int e = 0; e < NCAND / 4; ++e) {
    int ci = pi[e];
    const float4* crow = (const float4*)(xt + (bbase + ci) * 64);
    double a0 = 0.0, a1 = 0.0, a2 = 0.0, a3 = 0.0;
#pragma unroll
    for (int u = 0; u < 16; ++u) {
      float4 v = crow[u];
      a0 = fma((double)v.x, qd[u * 4 + 0], a0);
      a1 = fma((double)v.y, qd[u * 4 + 1], a1);
      a2 = fma((double)v.z, qd[u * 4 + 2], a2);
      a3 = fma((double)v.w, qd[u * 4 + 3], a3);
    }
    double dot = (a0 + a1) + (a2 + a3);
    double kd = fma(dot, -2.0, sqd[bbase + ci]) + 1024.0;  // in (894,1414)
    long long bits = (__double_as_longlong(kd) & ~0x1FFFLL) | (long long)ci;
    double v = __longlong_as_double(bits);
    if (ci == plocal) v = 1e300;  // self-exclusion
#pragma unroll
    for (int j = K_ - 1; j >= 1; --j)
      dl[j] = fmin(fmax(v, dl[j - 1]), dl[j]);
    dl[0] = fmin(dl[0], v);
  }
#pragma unroll
  for (int j = 0; j < K_; ++j) lists[tid][j] = dl[j];
  lists[tid][K_] = 1e300;  // sentinel
  __syncthreads();
  if (h == 0) {
    const double* L0 = lists[tid + 0];
    const double* L1 = lists[tid + 1];
    const double* L2 = lists[tid + 2];
    const double* L3 = lists[tid + 3];
    int h0 = 0, h1 = 0, h2 = 0, h3 = 0;
    int* o = idxf + (size_t)p * K_;
#pragma unroll 4
    for (int s = 0; s < K_; ++s) {
      double v0 = L0[h0], v1 = L1[h1], v2 = L2[h2], v3 = L3[h3];
      double m = fmin(fmin(v0, v1), fmin(v2, v3));
      o[s] = (int)(__double_as_longlong(m) & 0x1FFFLL);
      h0 += (v0 == m) ? 1 : 0;
      h1 += (v1 == m) ? 1 : 0;
      h2 += (v2 == m) ? 1 : 0;
      h3 += (v3 == m) ? 1 : 0;
    }
  }
}

// ---- Kernel 4: one WAVE per point. Lane (u=lane&15, jb=lane>>4); 5 rounds:
// lane loads 16B chunk u of neighbor jb+4r -> each 16-lane group reads a full
// 256B y1 row per instruction (no partial lines). max/min/sum/sumsq of the
// gathered y1 reduced across jb via shfl_xor(16,32); y2 applied once:
// max(h)=max(g)+y2, sum(h)=sum(g)+K*y2, sumsq(h)=sum(g^2)+2*y2*sum(g)+K*y2^2.
// 4 points per wave sequentially; BN sums -> LDS atomics -> 128 global/block.
__global__ __launch_bounds__(256) void stats_kernel(
    const float* __restrict__ y1, const float* __restrict__ y2,
    const int* __restrict__ idxf, float* __restrict__ maxh,
    float* __restrict__ minh, float* __restrict__ gsum,
    float* __restrict__ gsq) {
  __shared__ float lsum[64], lsq[64];
  int tid = threadIdx.x;
  if (tid < 64) { lsum[tid] = 0.f; lsq[tid] = 0.f; }
  __syncthreads();
  int wv = tid >> 6, lane = tid & 63;
  int u = lane & 15, jb = lane >> 4;
  int p0 = blockIdx.x * 16 + wv * 4;  // 16 contiguous points per block
  size_t nb = (size_t)((p0 >> 13) * N_);
  f32x4 css = {0.f, 0.f, 0.f, 0.f}, cqq = {0.f, 0.f, 0.f, 0.f};
#pragma unroll
  for (int it = 0; it < 4; ++it) {
    int p = p0 + it;
    int idxval = (lane < K_) ? idxf[(size_t)p * K_ + lane] : 0;
    int n0 = __shfl(idxval, jb, 64);
    int n1 = __shfl(idxval, jb + 4, 64);
    int n2 = __shfl(idxval, jb + 8, 64);
    int n3 = __shfl(idxval, jb + 12, 64);
    int n4 = __shfl(idxval, jb + 16, 64);
    f32x4 g0 = ((const f32x4*)(y1 + (nb + n0) * 64))[u];
    f32x4 g1 = ((const f32x4*)(y1 + (nb + n1) * 64))[u];
    f32x4 g2 = ((const f32x4*)(y1 + (nb + n2) * 64))[u];
    f32x4 g3 = ((const f32x4*)(y1 + (nb + n3) * 64))[u];
    f32x4 g4 = ((const f32x4*)(y1 + (nb + n4) * 64))[u];
    f32x4 mx = g0, mn = g0, sm = g0, s2 = g0 * g0;
    mx = max4(mx, g1); mn = min4(mn, g1); sm += g1; s2 += g1 * g1;
    mx = max4(mx, g2); mn = min4(mn, g2); sm += g2; s2 += g2 * g2;
    mx = max4(mx, g3); mn = min4(mn, g3); sm += g3; s2 += g3 * g3;
    mx = max4(mx, g4); mn = min4(mn, g4); sm += g4; s2 += g4 * g4;
#pragma unroll
    for (int c = 0; c < 4; ++c) {
      mx[c] = fmaxf(mx[c], __shfl_xor(mx[c], 16, 64));
      mx[c] = fmaxf(mx[c], __shfl_xor(mx[c], 32, 64));
      mn[c] = fminf(mn[c], __shfl_xor(mn[c], 16, 64));
      mn[c] = fminf(mn[c], __shfl_xor(mn[c], 32, 64));
      sm[c] += __shfl_xor(sm[c], 16, 64);
      sm[c] += __shfl_xor(sm[c], 32, 64);
      s2[c] += __shfl_xor(s2[c], 16, 64);
      s2[c] += __shfl_xor(s2[c], 32, 64);
    }
    if (jb == 0) {  // lanes 0..15: full 256B contiguous stores
      f32x4 y2c = ((const f32x4*)(y2 + (size_t)p * 64))[u];
      ((f32x4*)(maxh + (size_t)p * 64))[u] = mx + y2c;
      ((f32x4*)(minh + (size_t)p * 64))[u] = mn + y2c;
      css += sm + 20.0f * y2c;
      cqq += s2 + 2.0f * y2c * sm + 20.0f * y2c * y2c;
    }
  }
  if (jb == 0) {
#pragma unroll
    for (int c = 0; c < 4; ++c) {
      atomicAdd(&lsum[u * 4 + c], css[c]);
      atomicAdd(&lsq[u * 4 + c], cqq[c]);
    }
  }
  __syncthreads();
  if (tid < 64) {
    atomicAdd(&gsum[tid], lsum[tid]);
    atomicAdd(&gsq[tid], lsq[tid]);
  }
}

// ---- Kernel 5: affine + relu + max-over-k selection, transposed store ----
__global__ __launch_bounds__(256) void final_kernel(
    const float* __restrict__ maxh, const float* __restrict__ minh,
    const float* __restrict__ gsum, const float* __restrict__ gsq,
    const float* __restrict__ gamma, const float* __restrict__ beta,
    float* __restrict__ out) {
  __shared__ float sc[64], cc_[64];
  __shared__ float tile[64 * 65];
  int b = blockIdx.x >> 7;
  int n0 = (blockIdx.x & 127) * 64;
  int t = threadIdx.x;
  if (t < 64) {
    float mean = gsum[t] * (1.0f / CNT_TOTAL);
    float var = gsq[t] * (1.0f / CNT_TOTAL) - mean * mean;
    float s = gamma[t] * rsqrtf(var + BN_EPSF);
    sc[t] = s;
    cc_[t] = beta[t] - mean * s;
  }
  __syncthreads();
#pragma unroll
  for (int i = 0; i < 16; ++i) {
    int lin = i * 256 + t;
    int o = lin & 63, nl = lin >> 6;
    size_t off = ((size_t)(b * N_) + n0 + nl) * 64 + o;
    float s = sc[o];
    float v = (s >= 0.f) ? maxh[off] : minh[off];
    float val = fmaxf(fmaf(v, s, cc_[o]), 0.f);
    tile[o * 65 + nl] = val;
  }
  __syncthreads();
#pragma unroll
  for (int i = 0; i < 16; ++i) {
    int lin = i * 256 + t;
    int nl = lin & 63, o = lin >> 6;
    out[((size_t)(b * 64) + o) * N_ + n0 + nl] = tile[o * 65 + nl];
  }
}

extern "C" void kernel_launch(void* const* d_in, const int* in_sizes, int n_in,
                              void* d_out, int out_size, void* d_ws,
                              size_t ws_size, hipStream_t stream) {
  const float* x = (const float*)d_in[0];
  const float* W = (const float*)d_in[1];
  const float* gamma = (const float*)d_in[2];
  const float* beta = (const float*)d_in[3];
  float* out = (float*)d_out;

  char* ws = (char*)d_ws;
  size_t off = 0;
  auto alloc = [&](size_t bytes) {
    char* p = ws + off;
    off += (bytes + 255) & ~(size_t)255;
    return p;
  };
  float* xt = (float*)alloc((size_t)B_ * N_ * 64 * 4);
  _Float16* xt16 = (_Float16*)alloc((size_t)B_ * N_ * 64 * 2);
  float* y1 = (float*)alloc((size_t)B_ * N_ * 64 * 4);
  float* y2 = (float*)alloc((size_t)B_ * N_ * 64 * 4);
  float* sq = (float*)alloc((size_t)B_ * N_ * 4);
  double* sqd = (double*)alloc((size_t)B_ * N_ * 8);
  int* pidx = (int*)alloc((size_t)B_ * N_ * NCAND * 4);  // 33.5 MB
  float* maxh = (float*)alloc((size_t)B_ * N_ * 64 * 4);
  int* idxf = (int*)alloc((size_t)B_ * N_ * K_ * 4);
  float* gsum = (float*)alloc(256);
  float* gsq = (float*)alloc(256);
  // minh aliases pidx (pidx fully consumed by refine before stats runs)
  float* minh = (float*)pidx;

  hipMemsetAsync(gsum, 0, 256, stream);
  hipMemsetAsync(gsq, 0, 256, stream);

  prep_kernel<<<B_ * (N_ / 64), 256, 0, stream>>>(x, W, xt, xt16, sq, sqd,
                                                  y1, y2);
  knn_mfma_kernel<<<B_ * (N_ / 64) * NSPLIT, 256, 0, stream>>>(xt16, sq, pidx);
  refine_kernel<<<(B_ * N_) / 64, 256, 0, stream>>>(xt, sqd, pidx, idxf);
  stats_kernel<<<(B_ * N_) / 16, 256, 0, stream>>>(y1, y2, idxf, maxh, minh,
                                                   gsum, gsq);
  final_kernel<<<B_ * (N_ / 64), 256, 0, stream>>>(maxh, minh, gsum, gsq,
                                                   gamma, beta, out);
}

// Round 10
// 665.965 us; speedup vs baseline: 2.2165x; 1.0254x over previous
//
#include <hip/hip_runtime.h>

typedef _Float16 half8 __attribute__((ext_vector_type(8)));
typedef float f32x4 __attribute__((ext_vector_type(4)));

#define B_ 4
#define C_ 64
#define N_ 8192
#define K_ 20
#define LCELL 8                   // per-(split,class) sorted list depth
#define NSPLIT 2
#define NCAND (16 * LCELL * NSPLIT)  // 256 candidates per query into refine
#define CNT_TOTAL (B_ * N_ * K_)  // 655360
#define BN_EPSF 1e-5f

__device__ __forceinline__ f32x4 max4(f32x4 a, f32x4 b) {
  f32x4 r;
  r.x = fmaxf(a.x, b.x); r.y = fmaxf(a.y, b.y);
  r.z = fmaxf(a.z, b.z); r.w = fmaxf(a.w, b.w);
  return r;
}
__device__ __forceinline__ f32x4 min4(f32x4 a, f32x4 b) {
  f32x4 r;
  r.x = fminf(a.x, b.x); r.y = fminf(a.y, b.y);
  r.z = fminf(a.z, b.z); r.w = fminf(a.w, b.w);
  return r;
}

// ---- Kernel 1: transpose x -> xt (f32 + f16), per-point sq (f32+f64),
// y1 = xt*W1^T, y2 = xt*W2^T - y1. W row o==lane held in 128 VGPRs.
__global__ __launch_bounds__(256) void prep_kernel(
    const float* __restrict__ x, const float* __restrict__ W,
    float* __restrict__ xt, _Float16* __restrict__ xt16,
    float* __restrict__ sq, double* __restrict__ sqd,
    float* __restrict__ y1, float* __restrict__ y2) {
  __shared__ float xs[64 * 68];  // [n][c], stride 68 (16B-aligned rows)
  int b = blockIdx.x >> 7;
  int n0 = (blockIdx.x & 127) * 64;
  int t = threadIdx.x;
  int lane = t & 63;
  int wv = t >> 6;
#pragma unroll
  for (int i = 0; i < 16; ++i) {
    int lin = i * 256 + t;
    int c = lin >> 6, j = lin & 63;
    xs[j * 68 + c] = x[((b * 64 + c) * N_) + n0 + j];
  }
  // W row o = lane into registers (L1/L2-hot, 32 KB total)
  float4 w1[16], w2[16];
  const float4* wr = (const float4*)(W + lane * 128);
#pragma unroll
  for (int u = 0; u < 16; ++u) {
    w1[u] = wr[u];
    w2[u] = wr[16 + u];
  }
  __syncthreads();
#pragma unroll 2
  for (int i = 0; i < 16; ++i) {
    int nl = i * 4 + wv;
    const float4* xr = (const float4*)&xs[nl * 68];
    float d1 = 0.f, d2 = 0.f;
#pragma unroll
    for (int u = 0; u < 16; ++u) {
      float4 xv = xr[u];
      d1 = fmaf(xv.x, w1[u].x, d1); d1 = fmaf(xv.y, w1[u].y, d1);
      d1 = fmaf(xv.z, w1[u].z, d1); d1 = fmaf(xv.w, w1[u].w, d1);
      d2 = fmaf(xv.x, w2[u].x, d2); d2 = fmaf(xv.y, w2[u].y, d2);
      d2 = fmaf(xv.z, w2[u].z, d2); d2 = fmaf(xv.w, w2[u].w, d2);
    }
    int n = n0 + nl;
    y1[((b * N_) + n) * 64 + lane] = d1;
    y2[((b * N_) + n) * 64 + lane] = d2 - d1;
  }
#pragma unroll
  for (int i = 0; i < 16; ++i) {
    int lin = i * 256 + t;
    int c = lin & 63, nl = lin >> 6;
    float v = xs[nl * 68 + c];
    size_t o = ((size_t)(b * N_) + n0 + nl) * 64 + c;
    xt[o] = v;
    xt16[o] = (_Float16)v;
  }
  if (t < 64) {
    float s = 0.f;
    double sd = 0.0;
#pragma unroll
    for (int c = 0; c < 64; ++c) {
      float v = xs[t * 68 + c];
      s = fmaf(v, v, s);
      sd = fma((double)v, (double)v, sd);
    }
    sq[b * N_ + n0 + t] = s;
    sqd[b * N_ + n0 + t] = sd;
  }
}

// ---- Kernel 2: MFMA distance scan over one of 2 candidate splits (4096
// cands). Branchless clamp top-8 per (query,class). Packed key:
// (float_bits(sqc+512-2dot) & ~255) | tile_id(8b). Incremental pointers,
// 2x unrolled (no B-copy movs). __launch_bounds__(256,4): 128-VGPR budget
// so dl[] stays in arch VGPRs (no accvgpr round-trips).
__global__ __launch_bounds__(256, 4) void knn_mfma_kernel(
    const _Float16* __restrict__ xt16, const float* __restrict__ sq,
    int* __restrict__ pidx) {
  int t = threadIdx.x;
  int wave = t >> 6;
  int lane = t & 63;
  int col = lane & 15;
  int quad = lane >> 4;
  int blk = blockIdx.x;
  int split = blk & 1;
  int qt = (blk >> 1) & 127;
  int b = blk >> 8;
  int q0 = qt * 64 + wave * 16;
  size_t bbase = (size_t)b * N_;

  // A fragments: A[m=col][k=quad*8+j] -> query row q0+col
  const _Float16* arow = xt16 + (bbase + q0 + col) * 64;
  half8 A0 = *(const half8*)(arow + quad * 8);
  half8 A1 = *(const half8*)(arow + 32 + quad * 8);

  int dl[4][LCELL];
#pragma unroll
  for (int r = 0; r < 4; ++r)
#pragma unroll
    for (int j = 0; j < LCELL; ++j) dl[r][j] = 0x7fffffff;

  int c0 = split * (N_ / NSPLIT);
  const _Float16* bp = xt16 + (bbase + c0 + col) * 64 + quad * 8;
  const float* sp = sq + bbase + c0 + col;
  half8 B0 = *(const half8*)bp;
  half8 B1 = *(const half8*)(bp + 32);
  float sc = *sp;

  for (int ct = 0; ct < N_ / NSPLIT / 16; ct += 2) {
    // prefetch tile ct+1
    half8 C0 = *(const half8*)(bp + 1024);
    half8 C1 = *(const half8*)(bp + 1024 + 32);
    float sc1 = sp[16];

    f32x4 acc = {0.f, 0.f, 0.f, 0.f};
    acc = __builtin_amdgcn_mfma_f32_16x16x32_f16(A0, B0, acc, 0, 0, 0);
    acc = __builtin_amdgcn_mfma_f32_16x16x32_f16(A1, B1, acc, 0, 0, 0);
    float k512 = sc + 512.0f;
#pragma unroll
    for (int r = 0; r < 4; ++r) {
      float key = fmaf(acc[r], -2.0f, k512);  // positive by construction
      int v = (__float_as_int(key) & ~255) | ct;
#pragma unroll
      for (int j = LCELL - 1; j >= 1; --j)
        dl[r][j] = min(max(v, dl[r][j - 1]), dl[r][j]);
      dl[r][0] = min(dl[r][0], v);
    }

    // prefetch tile ct+2
    B0 = *(const half8*)(bp + 2048);
    B1 = *(const half8*)(bp + 2048 + 32);
    sc = sp[32];

    f32x4 acc2 = {0.f, 0.f, 0.f, 0.f};
    acc2 = __builtin_amdgcn_mfma_f32_16x16x32_f16(A0, C0, acc2, 0, 0, 0);
    acc2 = __builtin_amdgcn_mfma_f32_16x16x32_f16(A1, C1, acc2, 0, 0, 0);
    float k512b = sc1 + 512.0f;
    int ctb = ct + 1;
#pragma unroll
    for (int r = 0; r < 4; ++r) {
      float key = fmaf(acc2[r], -2.0f, k512b);
      int v = (__float_as_int(key) & ~255) | ctb;
#pragma unroll
      for (int j = LCELL - 1; j >= 1; --j)
        dl[r][j] = min(max(v, dl[r][j - 1]), dl[r][j]);
      dl[r][0] = min(dl[r][0], v);
    }
    bp += 2048;
    sp += 32;
  }
#pragma unroll
  for (int r = 0; r < 4; ++r) {
    int q = q0 + quad * 4 + r;
    int* o = pidx + (bbase + q) * NCAND + split * (16 * LCELL) + col * LCELL;
#pragma unroll
    for (int j = 0; j < LCELL; ++j)
      o[j] = ((dl[r][j] & 255) << 4) + col + c0;  // global candidate index
  }
}

// ---- Kernel 3: refinement v4 — one WAVE per point, cooperative fp64.
// Lane (u=lane&15 -> 4-dim chunk, g=lane>>4 -> candidate quarter). Per
// candidate: 16 lanes load one 16B chunk each (256B coalesced row), 4-dim
// fp64 partial dot, butterfly shfl_xor(1,2,4,8) -> exact fp64 dot on all
// lanes. key = sqd[ci] - 2*dot + 1024 (f64, same math as passing rounds),
// 13-bit index in low mantissa. Lane u keeps the 4 candidates e%16==u of
// its group (fixed slots), sorts 4, then wave-wide 20-step pop-min via
// 6-step fmin butterfly. No LDS, ~8 fp64 VGPRs of query state.
__global__ __launch_bounds__(256, 4) void refine_kernel(
    const float* __restrict__ xt, const double* __restrict__ sqd,
    const int* __restrict__ pidx, int* __restrict__ idxf) {
  int tid = threadIdx.x;
  int wave = tid >> 6, lane = tid & 63;
  int u = lane & 15, g = lane >> 4;
  int p = blockIdx.x * 4 + wave;  // global point id
  int b = p >> 13;
  size_t bbase = (size_t)b * N_;
  int plocal = p & (N_ - 1);

  // query chunk: dims u*4..u*4+3, fp64 (8 VGPRs)
  f32x4 qv = *(const f32x4*)(xt + (size_t)p * 64 + u * 4);
  double q0 = (double)qv.x, q1 = (double)qv.y;
  double q2 = (double)qv.z, q3 = (double)qv.w;

  const int* pi = pidx + (size_t)p * NCAND + g * 64;
  double kv0 = 1e300, kv1 = 1e300, kv2 = 1e300, kv3 = 1e300;
#pragma unroll
  for (int e = 0; e < 64; ++e) {
    int ci = pi[e];
    f32x4 cvf = *(const f32x4*)(xt + (bbase + ci) * 64 + u * 4);
    double a = q0 * (double)cvf.x;
    a = fma(q1, (double)cvf.y, a);
    a = fma(q2, (double)cvf.z, a);
    a = fma(q3, (double)cvf.w, a);
    a += __shfl_xor(a, 1, 64);
    a += __shfl_xor(a, 2, 64);
    a += __shfl_xor(a, 4, 64);
    a += __shfl_xor(a, 8, 64);  // all 16 lanes: exact fp64 dot
    double kd = fma(a, -2.0, sqd[bbase + ci]) + 1024.0;  // in (894,1414)
    long long bits = (__double_as_longlong(kd) & ~0x1FFFLL) | (long long)ci;
    double v = __longlong_as_double(bits);
    if (ci == plocal) v = 1e300;  // self-exclusion
    bool mine = ((e & 15) == u);
    if ((e >> 4) == 0) kv0 = mine ? v : kv0;
    else if ((e >> 4) == 1) kv1 = mine ? v : kv1;
    else if ((e >> 4) == 2) kv2 = mine ? v : kv2;
    else kv3 = mine ? v : kv3;
  }
  // sort 4 ascending (network: (0,1)(2,3)(0,2)(1,3)(1,2))
  {
    double lo, hi;
    lo = fmin(kv0, kv1); hi = fmax(kv0, kv1); kv0 = lo; kv1 = hi;
    lo = fmin(kv2, kv3); hi = fmax(kv2, kv3); kv2 = lo; kv3 = hi;
    lo = fmin(kv0, kv2); hi = fmax(kv0, kv2); kv0 = lo; kv2 = hi;
    lo = fmin(kv1, kv3); hi = fmax(kv1, kv3); kv1 = lo; kv3 = hi;
    lo = fmin(kv1, kv2); hi = fmax(kv1, kv2); kv1 = lo; kv2 = hi;
  }
  // wave-wide 20-step pop-min (keys unique -> exactly one head advances)
  int* o = idxf + (size_t)p * K_;
  double vh = kv0;
#pragma unroll
  for (int s = 0; s < K_; ++s) {
    double m = vh;
    m = fmin(m, __shfl_xor(m, 1, 64));
    m = fmin(m, __shfl_xor(m, 2, 64));
    m = fmin(m, __shfl_xor(m, 4, 64));
    m = fmin(m, __shfl_xor(m, 8, 64));
    m = fmin(m, __shfl_xor(m, 16, 64));
    m = fmin(m, __shfl_xor(m, 32, 64));
    if (lane == 0) o[s] = (int)(__double_as_longlong(m) & 0x1FFFLL);
    bool adv = (vh == m);
    vh = adv ? kv1 : vh;
    kv1 = adv ? kv2 : kv1;
    kv2 = adv ? kv3 : kv2;
    kv3 = adv ? 1e300 : kv3;
  }
}

// ---- Kernel 4: one WAVE per point. Lane (u=lane&15, jb=lane>>4); 5 rounds:
// lane loads 16B chunk u of neighbor jb+4r -> each 16-lane group reads a full
// 256B y1 row per instruction (no partial lines). max/min/sum/sumsq of the
// gathered y1 reduced across jb via shfl_xor(16,32); y2 applied once:
// max(h)=max(g)+y2, sum(h)=sum(g)+K*y2, sumsq(h)=sum(g^2)+2*y2*sum(g)+K*y2^2.
// 4 points per wave sequentially; BN sums -> LDS atomics -> 128 global/block.
__global__ __launch_bounds__(256) void stats_kernel(
    const float* __restrict__ y1, const float* __restrict__ y2,
    const int* __restrict__ idxf, float* __restrict__ maxh,
    float* __restrict__ minh, float* __restrict__ gsum,
    float* __restrict__ gsq) {
  __shared__ float lsum[64], lsq[64];
  int tid = threadIdx.x;
  if (tid < 64) { lsum[tid] = 0.f; lsq[tid] = 0.f; }
  __syncthreads();
  int wv = tid >> 6, lane = tid & 63;
  int u = lane & 15, jb = lane >> 4;
  int p0 = blockIdx.x * 16 + wv * 4;  // 16 contiguous points per block
  size_t nb = (size_t)((p0 >> 13) * N_);
  f32x4 css = {0.f, 0.f, 0.f, 0.f}, cqq = {0.f, 0.f, 0.f, 0.f};
#pragma unroll
  for (int it = 0; it < 4; ++it) {
    int p = p0 + it;
    int idxval = (lane < K_) ? idxf[(size_t)p * K_ + lane] : 0;
    int n0 = __shfl(idxval, jb, 64);
    int n1 = __shfl(idxval, jb + 4, 64);
    int n2 = __shfl(idxval, jb + 8, 64);
    int n3 = __shfl(idxval, jb + 12, 64);
    int n4 = __shfl(idxval, jb + 16, 64);
    f32x4 g0 = ((const f32x4*)(y1 + (nb + n0) * 64))[u];
    f32x4 g1 = ((const f32x4*)(y1 + (nb + n1) * 64))[u];
    f32x4 g2 = ((const f32x4*)(y1 + (nb + n2) * 64))[u];
    f32x4 g3 = ((const f32x4*)(y1 + (nb + n3) * 64))[u];
    f32x4 g4 = ((const f32x4*)(y1 + (nb + n4) * 64))[u];
    f32x4 mx = g0, mn = g0, sm = g0, s2 = g0 * g0;
    mx = max4(mx, g1); mn = min4(mn, g1); sm += g1; s2 += g1 * g1;
    mx = max4(mx, g2); mn = min4(mn, g2); sm += g2; s2 += g2 * g2;
    mx = max4(mx, g3); mn = min4(mn, g3); sm += g3; s2 += g3 * g3;
    mx = max4(mx, g4); mn = min4(mn, g4); sm += g4; s2 += g4 * g4;
#pragma unroll
    for (int c = 0; c < 4; ++c) {
      mx[c] = fmaxf(mx[c], __shfl_xor(mx[c], 16, 64));
      mx[c] = fmaxf(mx[c], __shfl_xor(mx[c], 32, 64));
      mn[c] = fminf(mn[c], __shfl_xor(mn[c], 16, 64));
      mn[c] = fminf(mn[c], __shfl_xor(mn[c], 32, 64));
      sm[c] += __shfl_xor(sm[c], 16, 64);
      sm[c] += __shfl_xor(sm[c], 32, 64);
      s2[c] += __shfl_xor(s2[c], 16, 64);
      s2[c] += __shfl_xor(s2[c], 32, 64);
    }
    if (jb == 0) {  // lanes 0..15: full 256B contiguous stores
      f32x4 y2c = ((const f32x4*)(y2 + (size_t)p * 64))[u];
      ((f32x4*)(maxh + (size_t)p * 64))[u] = mx + y2c;
      ((f32x4*)(minh + (size_t)p * 64))[u] = mn + y2c;
      css += sm + 20.0f * y2c;
      cqq += s2 + 2.0f * y2c * sm + 20.0f * y2c * y2c;
    }
  }
  if (jb == 0) {
#pragma unroll
    for (int c = 0; c < 4; ++c) {
      atomicAdd(&lsum[u * 4 + c], css[c]);
      atomicAdd(&lsq[u * 4 + c], cqq[c]);
    }
  }
  __syncthreads();
  if (tid < 64) {
    atomicAdd(&gsum[tid], lsum[tid]);
    atomicAdd(&gsq[tid], lsq[tid]);
  }
}

// ---- Kernel 5: affine + relu + max-over-k selection, transposed store ----
__global__ __launch_bounds__(256) void final_kernel(
    const float* __restrict__ maxh, const float* __restrict__ minh,
    const float* __restrict__ gsum, const float* __restrict__ gsq,
    const float* __restrict__ gamma, const float* __restrict__ beta,
    float* __restrict__ out) {
  __shared__ float sc[64], cc_[64];
  __shared__ float tile[64 * 65];
  int b = blockIdx.x >> 7;
  int n0 = (blockIdx.x & 127) * 64;
  int t = threadIdx.x;
  if (t < 64) {
    float mean = gsum[t] * (1.0f / CNT_TOTAL);
    float var = gsq[t] * (1.0f / CNT_TOTAL) - mean * mean;
    float s = gamma[t] * rsqrtf(var + BN_EPSF);
    sc[t] = s;
    cc_[t] = beta[t] - mean * s;
  }
  __syncthreads();
#pragma unroll
  for (int i = 0; i < 16; ++i) {
    int lin = i * 256 + t;
    int o = lin & 63, nl = lin >> 6;
    size_t off = ((size_t)(b * N_) + n0 + nl) * 64 + o;
    float s = sc[o];
    float v = (s >= 0.f) ? maxh[off] : minh[off];
    float val = fmaxf(fmaf(v, s, cc_[o]), 0.f);
    tile[o * 65 + nl] = val;
  }
  __syncthreads();
#pragma unroll
  for (int i = 0; i < 16; ++i) {
    int lin = i * 256 + t;
    int nl = lin & 63, o = lin >> 6;
    out[((size_t)(b * 64) + o) * N_ + n0 + nl] = tile[o * 65 + nl];
  }
}

extern "C" void kernel_launch(void* const* d_in, const int* in_sizes, int n_in,
                              void* d_out, int out_size, void* d_ws,
                              size_t ws_size, hipStream_t stream) {
  const float* x = (const float*)d_in[0];
  const float* W = (const float*)d_in[1];
  const float* gamma = (const float*)d_in[2];
  const float* beta = (const float*)d_in[3];
  float* out = (float*)d_out;

  char* ws = (char*)d_ws;
  size_t off = 0;
  auto alloc = [&](size_t bytes) {
    char* p = ws + off;
    off += (bytes + 255) & ~(size_t)255;
    return p;
  };
  float* xt = (float*)alloc((size_t)B_ * N_ * 64 * 4);
  _Float16* xt16 = (_Float16*)alloc((size_t)B_ * N_ * 64 * 2);
  float* y1 = (float*)alloc((size_t)B_ * N_ * 64 * 4);
  float* y2 = (float*)alloc((size_t)B_ * N_ * 64 * 4);
  float* sq = (float*)alloc((size_t)B_ * N_ * 4);
  double* sqd = (double*)alloc((size_t)B_ * N_ * 8);
  int* pidx = (int*)alloc((size_t)B_ * N_ * NCAND * 4);  // 33.5 MB
  float* maxh = (float*)alloc((size_t)B_ * N_ * 64 * 4);
  int* idxf = (int*)alloc((size_t)B_ * N_ * K_ * 4);
  float* gsum = (float*)alloc(256);
  float* gsq = (float*)alloc(256);
  // minh aliases pidx (pidx fully consumed by refine before stats runs)
  float* minh = (float*)pidx;

  hipMemsetAsync(gsum, 0, 256, stream);
  hipMemsetAsync(gsq, 0, 256, stream);

  prep_kernel<<<B_ * (N_ / 64), 256, 0, stream>>>(x, W, xt, xt16, sq, sqd,
                                                  y1, y2);
  knn_mfma_kernel<<<B_ * (N_ / 64) * NSPLIT, 256, 0, stream>>>(xt16, sq, pidx);
  refine_kernel<<<(B_ * N_) / 4, 256, 0, stream>>>(xt, sqd, pidx, idxf);
  stats_kernel<<<(B_ * N_) / 16, 256, 0, stream>>>(y1, y2, idxf, maxh, minh,
                                                   gsum, gsq);
  final_kernel<<<B_ * (N_ / 64), 256, 0, stream>>>(maxh, minh, gsum, gsq,
                                                   gamma, beta, out);
}